// Round 2
// baseline (3478.121 us; speedup 1.0000x reference)
//
#include <hip/hip_runtime.h>
#include <hip/hip_bf16.h>

#define IN_F 128
#define HEADS 4
#define OUT_F 32
#define NEG_SLOPE 0.2f

// ---------------------------------------------------------------------------
// K0: init out with bias, zero softmax denominators
// ---------------------------------------------------------------------------
__global__ __launch_bounds__(256) void init_kernel(float* __restrict__ out,
                                                   const float* __restrict__ bias,
                                                   float* __restrict__ denom,
                                                   int n_out, int n_den) {
    int i = blockIdx.x * 256 + threadIdx.x;
    if (i < n_out) out[i] = bias[i & (IN_F - 1)];
    if (i < n_den) denom[i] = 0.f;
}

// ---------------------------------------------------------------------------
// K1: h = x @ W   (fp32, vector ALU — no fp32 MFMA on CDNA4)
// Block: 256 threads -> 8 rows x 128 cols. x rows staged in LDS,
// W (64 KB) stays hot in L1/L2. Each thread: 1 row x 4 cols, K=128 loop.
// ---------------------------------------------------------------------------
__global__ __launch_bounds__(256) void gemm_kernel(const float* __restrict__ x,
                                                   const float* __restrict__ W,
                                                   float* __restrict__ h,
                                                   int n_nodes) {
    __shared__ float xs[8 * 128];
    int tid = threadIdx.x;
    int r   = tid >> 5;          // 0..7  local row
    int c4  = (tid & 31) << 2;   // 0,4,...,124 col
    int grow = blockIdx.x * 8 + r;

    float4 xv = make_float4(0.f, 0.f, 0.f, 0.f);
    if (grow < n_nodes) xv = *(const float4*)(x + (size_t)grow * IN_F + c4);
    *(float4*)(xs + r * IN_F + c4) = xv;
    __syncthreads();

    const float* xrow = xs + r * IN_F;
    float ax = 0.f, ay = 0.f, az = 0.f, aw = 0.f;
#pragma unroll 8
    for (int k = 0; k < 128; ++k) {
        float xk = xrow[k];
        float4 wv = *(const float4*)(W + k * IN_F + c4);
        ax += xk * wv.x; ay += xk * wv.y; az += xk * wv.z; aw += xk * wv.w;
    }
    if (grow < n_nodes) {
        float4 o; o.x = ax; o.y = ay; o.z = az; o.w = aw;
        *(float4*)(h + (size_t)grow * IN_F + c4) = o;
    }
}

// ---------------------------------------------------------------------------
// K2: per-node attention halves: s_src[n*4+hh] = dot(h[n,hh,:], att_src[hh,:])
// 8 lanes per (n,hh) group, float4 loads, shfl-xor tree reduce.
// ---------------------------------------------------------------------------
__global__ __launch_bounds__(256) void attn_halves_kernel(const float* __restrict__ h,
                                                          const float* __restrict__ att_src,
                                                          const float* __restrict__ att_dst,
                                                          float* __restrict__ s_src,
                                                          float* __restrict__ s_dst,
                                                          int n_groups) {
    int gid   = blockIdx.x * 256 + threadIdx.x;
    int group = gid >> 3;      // (n, hh) pair
    int l8    = gid & 7;
    if (group >= n_groups) return;
    int hh = group & 3;

    // group*32 == n*128 + hh*32
    float4 hv = *(const float4*)(h + (size_t)group * OUT_F + l8 * 4);
    float4 a1 = *(const float4*)(att_src + hh * OUT_F + l8 * 4);
    float4 a2 = *(const float4*)(att_dst + hh * OUT_F + l8 * 4);

    float ds_ = hv.x * a1.x + hv.y * a1.y + hv.z * a1.z + hv.w * a1.w;
    float dd_ = hv.x * a2.x + hv.y * a2.y + hv.z * a2.z + hv.w * a2.w;
    ds_ += __shfl_xor(ds_, 1); ds_ += __shfl_xor(ds_, 2); ds_ += __shfl_xor(ds_, 4);
    dd_ += __shfl_xor(dd_, 1); dd_ += __shfl_xor(dd_, 2); dd_ += __shfl_xor(dd_, 4);
    if (l8 == 0) { s_src[group] = ds_; s_dst[group] = dd_; }
}

// ---------------------------------------------------------------------------
// K3: softmax denominators. One thread per edge (incl. self-loops), 4 heads.
// No segment_max needed: logits bounded (~|e|<10 by construction), exp is
// safe in fp32 and alpha = exp(e)/sum exp(e) is shift-invariant.
// ---------------------------------------------------------------------------
__global__ __launch_bounds__(256) void edge_denom_kernel(const int* __restrict__ ei,
                                                         const float* __restrict__ s_src,
                                                         const float* __restrict__ s_dst,
                                                         float* __restrict__ denom,
                                                         int nE, int nTot) {
    int e = blockIdx.x * 256 + threadIdx.x;
    if (e >= nTot) return;
    int s, d;
    if (e < nE) { s = ei[e]; d = ei[nE + e]; }
    else        { s = e - nE; d = s; }

    float4 as = *(const float4*)(s_src + (size_t)s * 4);
    float4 ad = *(const float4*)(s_dst + (size_t)d * 4);
    float v0 = as.x + ad.x, v1 = as.y + ad.y, v2 = as.z + ad.z, v3 = as.w + ad.w;
    v0 = v0 > 0.f ? v0 : NEG_SLOPE * v0;
    v1 = v1 > 0.f ? v1 : NEG_SLOPE * v1;
    v2 = v2 > 0.f ? v2 : NEG_SLOPE * v2;
    v3 = v3 > 0.f ? v3 : NEG_SLOPE * v3;
    atomicAdd(denom + (size_t)d * 4 + 0, expf(v0));
    atomicAdd(denom + (size_t)d * 4 + 1, expf(v1));
    atomicAdd(denom + (size_t)d * 4 + 2, expf(v2));
    atomicAdd(denom + (size_t)d * 4 + 3, expf(v3));
}

// ---------------------------------------------------------------------------
// K4: weighted scatter-aggregate. 32 lanes per edge, each lane owns 4 feats.
// h[src] row gather (512B, LLC-resident) + 4 fp32 atomicAdds into out[dst].
// ---------------------------------------------------------------------------
__global__ __launch_bounds__(256) void edge_aggregate_kernel(const int* __restrict__ ei,
                                                             const float* __restrict__ hfeat,
                                                             const float* __restrict__ s_src,
                                                             const float* __restrict__ s_dst,
                                                             const float* __restrict__ denom,
                                                             float* __restrict__ out,
                                                             int nE, int nTot) {
    int gid  = blockIdx.x * 256 + threadIdx.x;
    int e    = gid >> 5;
    int lane = gid & 31;
    if (e >= nTot) return;
    int s, d;
    if (e < nE) { s = ei[e]; d = ei[nE + e]; }
    else        { s = e - nE; d = s; }

    int hh = lane >> 3;
    float v = s_src[(size_t)s * 4 + hh] + s_dst[(size_t)d * 4 + hh];
    v = v > 0.f ? v : NEG_SLOPE * v;
    float alpha = expf(v) / (denom[(size_t)d * 4 + hh] + 1e-16f);

    float4 hv = *(const float4*)(hfeat + (size_t)s * IN_F + lane * 4);
    float* op = out + (size_t)d * IN_F + lane * 4;
    atomicAdd(op + 0, hv.x * alpha);
    atomicAdd(op + 1, hv.y * alpha);
    atomicAdd(op + 2, hv.z * alpha);
    atomicAdd(op + 3, hv.w * alpha);
}

// ---------------------------------------------------------------------------
extern "C" void kernel_launch(void* const* d_in, const int* in_sizes, int n_in,
                              void* d_out, int out_size, void* d_ws, size_t ws_size,
                              hipStream_t stream) {
    const float* x       = (const float*)d_in[0];
    const int*   ei      = (const int*)d_in[1];   // harness stages integers as int32
    const float* W       = (const float*)d_in[2];
    const float* att_src = (const float*)d_in[3];
    const float* att_dst = (const float*)d_in[4];
    const float* bias    = (const float*)d_in[5];
    float*       out     = (float*)d_out;

    const int N    = in_sizes[0] / IN_F;   // 100000
    const int E    = in_sizes[1] / 2;      // 1600000
    const int ETOT = E + N;                // + self loops

    // workspace layout (fp32): h [N*128], s_src [N*4], s_dst [N*4], denom [N*4]
    char*  wsp   = (char*)d_ws;
    float* h     = (float*)wsp;
    float* s_src = (float*)(wsp + (size_t)N * IN_F * 4);
    float* s_dst = s_src + (size_t)N * HEADS;
    float* denom = s_dst + (size_t)N * HEADS;

    const int n_out = N * IN_F;
    const int n_den = N * HEADS;

    // K0: out = bias, denom = 0
    init_kernel<<<(n_out + 255) / 256, 256, 0, stream>>>(out, bias, denom, n_out, n_den);

    // K1: h = x @ W
    gemm_kernel<<<(N + 7) / 8, 256, 0, stream>>>(x, W, h, N);

    // K2: attention halves
    {
        int n_groups = N * HEADS;
        int nthr = n_groups * 8;
        attn_halves_kernel<<<(nthr + 255) / 256, 256, 0, stream>>>(h, att_src, att_dst,
                                                                   s_src, s_dst, n_groups);
    }

    // K3: softmax denominators
    edge_denom_kernel<<<(ETOT + 255) / 256, 256, 0, stream>>>(ei, s_src, s_dst, denom, E, ETOT);

    // K4: aggregate
    {
        long long nthr = (long long)ETOT * 32;
        int nblk = (int)((nthr + 255) / 256);
        edge_aggregate_kernel<<<nblk, 256, 0, stream>>>(ei, h, s_src, s_dst, denom, out, E, ETOT);
    }
}

// Round 3
// 637.577 us; speedup vs baseline: 5.4552x; 5.4552x over previous
//
#include <hip/hip_runtime.h>
#include <hip/hip_bf16.h>

#define IN_F 128
#define HEADS 4
#define OUT_F 32
#define NEG_SLOPE 0.2f

// ---------------------------------------------------------------------------
// K1: h = x @ W   (fp32, vector ALU — no fp32 MFMA on CDNA4)
// ---------------------------------------------------------------------------
__global__ __launch_bounds__(256) void gemm_kernel(const float* __restrict__ x,
                                                   const float* __restrict__ W,
                                                   float* __restrict__ h,
                                                   int n_nodes) {
    __shared__ float xs[8 * 128];
    int tid = threadIdx.x;
    int r   = tid >> 5;          // 0..7  local row
    int c4  = (tid & 31) << 2;   // 0,4,...,124 col
    int grow = blockIdx.x * 8 + r;

    float4 xv = make_float4(0.f, 0.f, 0.f, 0.f);
    if (grow < n_nodes) xv = *(const float4*)(x + (size_t)grow * IN_F + c4);
    *(float4*)(xs + r * IN_F + c4) = xv;
    __syncthreads();

    const float* xrow = xs + r * IN_F;
    float ax = 0.f, ay = 0.f, az = 0.f, aw = 0.f;
#pragma unroll 8
    for (int k = 0; k < 128; ++k) {
        float xk = xrow[k];
        float4 wv = *(const float4*)(W + k * IN_F + c4);
        ax += xk * wv.x; ay += xk * wv.y; az += xk * wv.z; aw += xk * wv.w;
    }
    if (grow < n_nodes) {
        float4 o; o.x = ax; o.y = ay; o.z = az; o.w = aw;
        *(float4*)(h + (size_t)grow * IN_F + c4) = o;
    }
}

// ---------------------------------------------------------------------------
// K2: per-node attention halves
// ---------------------------------------------------------------------------
__global__ __launch_bounds__(256) void attn_halves_kernel(const float* __restrict__ h,
                                                          const float* __restrict__ att_src,
                                                          const float* __restrict__ att_dst,
                                                          float* __restrict__ s_src,
                                                          float* __restrict__ s_dst,
                                                          int n_groups) {
    int gid   = blockIdx.x * 256 + threadIdx.x;
    int group = gid >> 3;      // (n, hh) pair
    int l8    = gid & 7;
    if (group >= n_groups) return;
    int hh = group & 3;

    float4 hv = *(const float4*)(h + (size_t)group * OUT_F + l8 * 4);
    float4 a1 = *(const float4*)(att_src + hh * OUT_F + l8 * 4);
    float4 a2 = *(const float4*)(att_dst + hh * OUT_F + l8 * 4);

    float ds_ = hv.x * a1.x + hv.y * a1.y + hv.z * a1.z + hv.w * a1.w;
    float dd_ = hv.x * a2.x + hv.y * a2.y + hv.z * a2.z + hv.w * a2.w;
    ds_ += __shfl_xor(ds_, 1); ds_ += __shfl_xor(ds_, 2); ds_ += __shfl_xor(ds_, 4);
    dd_ += __shfl_xor(dd_, 1); dd_ += __shfl_xor(dd_, 2); dd_ += __shfl_xor(dd_, 4);
    if (l8 == 0) { s_src[group] = ds_; s_dst[group] = dd_; }
}

// ---------------------------------------------------------------------------
// CSR build: histogram -> 3-phase exclusive scan -> scatter fill
// ---------------------------------------------------------------------------
__global__ __launch_bounds__(256) void zero_deg_kernel(int* __restrict__ deg, int n) {
    int i = blockIdx.x * 256 + threadIdx.x;
    if (i < n) deg[i] = 0;
}

__global__ __launch_bounds__(256) void count_kernel(const int* __restrict__ ei,
                                                    int* __restrict__ deg, int E) {
    int e = blockIdx.x * 256 + threadIdx.x;
    if (e < E) atomicAdd(&deg[ei[E + e]], 1);
}

// scan phase 1: per-1024-chunk sums
__global__ __launch_bounds__(256) void scan1_kernel(const int* __restrict__ deg,
                                                    int* __restrict__ blksum, int N) {
    __shared__ int s[256];
    int base = blockIdx.x * 1024 + threadIdx.x * 4;
    int sum = 0;
#pragma unroll
    for (int j = 0; j < 4; ++j) { int i = base + j; if (i < N) sum += deg[i]; }
    s[threadIdx.x] = sum;
    __syncthreads();
    for (int off = 128; off > 0; off >>= 1) {
        if (threadIdx.x < off) s[threadIdx.x] += s[threadIdx.x + off];
        __syncthreads();
    }
    if (threadIdx.x == 0) blksum[blockIdx.x] = s[0];
}

// scan phase 2: single-block exclusive scan of chunk sums (nblk <= 256)
__global__ __launch_bounds__(256) void scan2_kernel(const int* __restrict__ blksum,
                                                    int* __restrict__ blkoff, int nblk) {
    __shared__ int s[256];
    int t = threadIdx.x;
    int v = (t < nblk) ? blksum[t] : 0;
    s[t] = v;
    __syncthreads();
    for (int off = 1; off < 256; off <<= 1) {
        int add = (t >= off) ? s[t - off] : 0;
        __syncthreads();
        s[t] += add;
        __syncthreads();
    }
    if (t < nblk) blkoff[t] = s[t] - v;   // exclusive
}

// scan phase 3: per-element exclusive prefix -> rowptr; also init cursor(=deg)
__global__ __launch_bounds__(256) void scan3_kernel(int* __restrict__ deg,
                                                    const int* __restrict__ blkoff,
                                                    int* __restrict__ rowptr, int N) {
    __shared__ int s[256];
    int t = threadIdx.x;
    int base = blockIdx.x * 1024 + t * 4;
    int d[4];
    int loc = 0;
#pragma unroll
    for (int j = 0; j < 4; ++j) { int i = base + j; d[j] = (i < N) ? deg[i] : 0; loc += d[j]; }
    s[t] = loc;
    __syncthreads();
    for (int off = 1; off < 256; off <<= 1) {
        int add = (t >= off) ? s[t - off] : 0;
        __syncthreads();
        s[t] += add;
        __syncthreads();
    }
    int run = s[t] - loc + blkoff[blockIdx.x];   // exclusive prefix for this thread
#pragma unroll
    for (int j = 0; j < 4; ++j) {
        int i = base + j;
        if (i < N) {
            rowptr[i] = run;
            deg[i]    = run;        // reuse deg as the scatter cursor
            run += d[j];
            if (i == N - 1) rowptr[N] = run;
        }
    }
}

__global__ __launch_bounds__(256) void fill_kernel(const int* __restrict__ ei,
                                                   int* __restrict__ cursor,
                                                   int* __restrict__ esrc, int E) {
    int e = blockIdx.x * 256 + threadIdx.x;
    if (e >= E) return;
    int s = ei[e], d = ei[E + e];
    int pos = atomicAdd(&cursor[d], 1);
    esrc[pos] = s;
}

// ---------------------------------------------------------------------------
// K6: gather-reduce aggregate. One wave (64 lanes) per dst node; lane owns
// 2 features (float2). Accumulate sum(exp(e)*h[src]) and sum(exp(e)) in
// registers, normalize once, single coalesced 512B row write. Zero atomics.
// Self-loop handled inline. Softmax is shift-invariant; logits are O(8) so
// unshifted exp is safe in fp32.
// ---------------------------------------------------------------------------
__global__ __launch_bounds__(256) void aggregate_kernel(const int* __restrict__ rowptr,
                                                        const int* __restrict__ esrc,
                                                        const float* __restrict__ hfeat,
                                                        const float* __restrict__ s_src,
                                                        const float* __restrict__ s_dst,
                                                        const float* __restrict__ bias,
                                                        float* __restrict__ out,
                                                        int N) {
    int wid  = threadIdx.x >> 6;           // wave in block (0..3)
    int lane = threadIdx.x & 63;
    int n = blockIdx.x * 4 + wid;
    if (n >= N) return;

    int f  = lane * 2;                     // this lane's 2 features
    int hh = lane >> 4;                    // head = f/32

    float sdst = s_dst[(size_t)n * 4 + hh];

    // self-loop message
    float e0 = s_src[(size_t)n * 4 + hh] + sdst;
    e0 = e0 > 0.f ? e0 : NEG_SLOPE * e0;
    float p0 = expf(e0);
    float2 hv = *(const float2*)(hfeat + (size_t)n * IN_F + f);
    float accx = p0 * hv.x, accy = p0 * hv.y, den = p0;

    int k0 = rowptr[n], k1 = rowptr[n + 1];
    for (int base = k0; base < k1; base += 64) {
        int cnt = k1 - base; if (cnt > 64) cnt = 64;
        int msrc = (lane < cnt) ? esrc[base + lane] : 0;
        for (int j = 0; j < cnt; ++j) {
            int src = __shfl(msrc, j);
            float ss = s_src[(size_t)src * 4 + hh];
            float ee = ss + sdst;
            ee = ee > 0.f ? ee : NEG_SLOPE * ee;
            float pp = expf(ee);
            float2 hs = *(const float2*)(hfeat + (size_t)src * IN_F + f);
            accx += pp * hs.x;
            accy += pp * hs.y;
            den  += pp;
        }
    }

    float inv = 1.f / (den + 1e-16f);
    float2 o;
    o.x = accx * inv + bias[f];
    o.y = accy * inv + bias[f + 1];
    *(float2*)(out + (size_t)n * IN_F + f) = o;
}

// ---------------------------------------------------------------------------
extern "C" void kernel_launch(void* const* d_in, const int* in_sizes, int n_in,
                              void* d_out, int out_size, void* d_ws, size_t ws_size,
                              hipStream_t stream) {
    const float* x       = (const float*)d_in[0];
    const int*   ei      = (const int*)d_in[1];   // harness stages integers as int32
    const float* W       = (const float*)d_in[2];
    const float* att_src = (const float*)d_in[3];
    const float* att_dst = (const float*)d_in[4];
    const float* bias    = (const float*)d_in[5];
    float*       out     = (float*)d_out;

    const int N = in_sizes[0] / IN_F;   // 100000
    const int E = in_sizes[1] / 2;      // 1600000

    // workspace layout (bytes):
    //   h      : N*128*4 = 51.2MB
    //   s_src  : N*4*4
    //   s_dst  : N*4*4
    //   deg    : N*4        (reused as scatter cursor)
    //   rowptr : (N+1)*4
    //   blksum : 256*4
    //   blkoff : 256*4
    //   esrc   : E*4
    char*  wsp    = (char*)d_ws;
    float* h      = (float*)wsp;                      wsp += (size_t)N * IN_F * 4;
    float* s_src  = (float*)wsp;                      wsp += (size_t)N * HEADS * 4;
    float* s_dst  = (float*)wsp;                      wsp += (size_t)N * HEADS * 4;
    int*   deg    = (int*)wsp;                        wsp += (size_t)N * 4;
    int*   rowptr = (int*)wsp;                        wsp += (size_t)(N + 1) * 4;
    int*   blksum = (int*)wsp;                        wsp += 256 * 4;
    int*   blkoff = (int*)wsp;                        wsp += 256 * 4;
    int*   esrc   = (int*)wsp;

    const int nblk_scan = (N + 1023) / 1024;          // 98 <= 256

    // histogram + projection + attention halves (independent order, same stream)
    zero_deg_kernel<<<(N + 255) / 256, 256, 0, stream>>>(deg, N);
    count_kernel<<<(E + 255) / 256, 256, 0, stream>>>(ei, deg, E);
    gemm_kernel<<<(N + 7) / 8, 256, 0, stream>>>(x, W, h, N);
    {
        int n_groups = N * HEADS;
        int nthr = n_groups * 8;
        attn_halves_kernel<<<(nthr + 255) / 256, 256, 0, stream>>>(h, att_src, att_dst,
                                                                   s_src, s_dst, n_groups);
    }

    // exclusive scan deg -> rowptr (and cursor)
    scan1_kernel<<<nblk_scan, 256, 0, stream>>>(deg, blksum, N);
    scan2_kernel<<<1, 256, 0, stream>>>(blksum, blkoff, nblk_scan);
    scan3_kernel<<<nblk_scan, 256, 0, stream>>>(deg, blkoff, rowptr, N);

    // scatter sources into CSR
    fill_kernel<<<(E + 255) / 256, 256, 0, stream>>>(ei, deg, esrc, E);

    // gather-reduce per dst node
    aggregate_kernel<<<(N + 3) / 4, 256, 0, stream>>>(rowptr, esrc, h, s_src, s_dst,
                                                      bias, out, N);
}

// Round 4
// 500.915 us; speedup vs baseline: 6.9435x; 1.2728x over previous
//
#include <hip/hip_runtime.h>
#include <hip/hip_bf16.h>

#define IN_F 128
#define HEADS 4
#define OUT_F 32
#define NEG_SLOPE 0.2f

// ---------------------------------------------------------------------------
// K1: h = x @ W   (fp32 vector ALU — no fp32 MFMA on CDNA4)
// Register-blocked: block = 32 rows x 128 cols, thread = 4x4 tile.
// Per k-step: 16 FMA : 1 ds_read_b128 (x, transposed LDS) : 1 float4 W (L2).
// xs_t stride 36 floats: float4 alignment holds (k*36+r4 % 4 == 0), staging
// writes are 32-consecutive-scalar per wave-half (conflict-free), compute
// reads are wave-broadcast (free).
// ---------------------------------------------------------------------------
__global__ __launch_bounds__(256) void gemm_kernel(const float* __restrict__ x,
                                                   const float* __restrict__ W,
                                                   float* __restrict__ h,
                                                   int n_nodes) {
    __shared__ float xs_t[128 * 36];   // [k][row], stride 36

    int tid = threadIdx.x;

    // ---- stage x tile (32 rows x 128 k), transposed ----
    {
        int row   = tid & 31;
        int kbase = (tid >> 5) << 4;           // 0,16,...,112
        int grow  = blockIdx.x * 32 + row;
        const float* xp = x + (size_t)grow * IN_F + kbase;
        bool ok = (grow < n_nodes);
#pragma unroll
        for (int j = 0; j < 4; ++j) {
            float4 xv = ok ? *(const float4*)(xp + j * 4)
                           : make_float4(0.f, 0.f, 0.f, 0.f);
            int k = kbase + j * 4;
            xs_t[(k + 0) * 36 + row] = xv.x;
            xs_t[(k + 1) * 36 + row] = xv.y;
            xs_t[(k + 2) * 36 + row] = xv.z;
            xs_t[(k + 3) * 36 + row] = xv.w;
        }
    }
    __syncthreads();

    // ---- compute 4 rows x 4 cols per thread ----
    int c4 = (tid & 31) << 2;                  // col base 0..124
    int r4 = (tid >> 5) << 2;                  // local row base 0..28

    float4 acc0 = make_float4(0.f, 0.f, 0.f, 0.f);
    float4 acc1 = make_float4(0.f, 0.f, 0.f, 0.f);
    float4 acc2 = make_float4(0.f, 0.f, 0.f, 0.f);
    float4 acc3 = make_float4(0.f, 0.f, 0.f, 0.f);

#pragma unroll 8
    for (int k = 0; k < 128; ++k) {
        float4 xv = *(const float4*)(xs_t + k * 36 + r4);   // 4 rows, broadcast
        float4 wv = *(const float4*)(W + k * IN_F + c4);    // 4 cols, L2-hot
        acc0.x += xv.x * wv.x; acc0.y += xv.x * wv.y; acc0.z += xv.x * wv.z; acc0.w += xv.x * wv.w;
        acc1.x += xv.y * wv.x; acc1.y += xv.y * wv.y; acc1.z += xv.y * wv.z; acc1.w += xv.y * wv.w;
        acc2.x += xv.z * wv.x; acc2.y += xv.z * wv.y; acc2.z += xv.z * wv.z; acc2.w += xv.z * wv.w;
        acc3.x += xv.w * wv.x; acc3.y += xv.w * wv.y; acc3.z += xv.w * wv.z; acc3.w += xv.w * wv.w;
    }

    int grow = blockIdx.x * 32 + r4;
    if (grow + 0 < n_nodes) *(float4*)(h + (size_t)(grow + 0) * IN_F + c4) = acc0;
    if (grow + 1 < n_nodes) *(float4*)(h + (size_t)(grow + 1) * IN_F + c4) = acc1;
    if (grow + 2 < n_nodes) *(float4*)(h + (size_t)(grow + 2) * IN_F + c4) = acc2;
    if (grow + 3 < n_nodes) *(float4*)(h + (size_t)(grow + 3) * IN_F + c4) = acc3;
}

// ---------------------------------------------------------------------------
// K2: per-node attention halves
// ---------------------------------------------------------------------------
__global__ __launch_bounds__(256) void attn_halves_kernel(const float* __restrict__ h,
                                                          const float* __restrict__ att_src,
                                                          const float* __restrict__ att_dst,
                                                          float* __restrict__ s_src,
                                                          float* __restrict__ s_dst,
                                                          int n_groups) {
    int gid   = blockIdx.x * 256 + threadIdx.x;
    int group = gid >> 3;      // (n, hh) pair
    int l8    = gid & 7;
    if (group >= n_groups) return;
    int hh = group & 3;

    float4 hv = *(const float4*)(h + (size_t)group * OUT_F + l8 * 4);
    float4 a1 = *(const float4*)(att_src + hh * OUT_F + l8 * 4);
    float4 a2 = *(const float4*)(att_dst + hh * OUT_F + l8 * 4);

    float ds_ = hv.x * a1.x + hv.y * a1.y + hv.z * a1.z + hv.w * a1.w;
    float dd_ = hv.x * a2.x + hv.y * a2.y + hv.z * a2.z + hv.w * a2.w;
    ds_ += __shfl_xor(ds_, 1); ds_ += __shfl_xor(ds_, 2); ds_ += __shfl_xor(ds_, 4);
    dd_ += __shfl_xor(dd_, 1); dd_ += __shfl_xor(dd_, 2); dd_ += __shfl_xor(dd_, 4);
    if (l8 == 0) { s_src[group] = ds_; s_dst[group] = dd_; }
}

// ---------------------------------------------------------------------------
// CSR build: histogram -> 3-phase exclusive scan -> scatter fill
// ---------------------------------------------------------------------------
__global__ __launch_bounds__(256) void zero_deg_kernel(int* __restrict__ deg, int n) {
    int i = blockIdx.x * 256 + threadIdx.x;
    if (i < n) deg[i] = 0;
}

__global__ __launch_bounds__(256) void count_kernel(const int* __restrict__ ei,
                                                    int* __restrict__ deg, int E) {
    int e = blockIdx.x * 256 + threadIdx.x;
    if (e < E) atomicAdd(&deg[ei[E + e]], 1);
}

// scan phase 1: per-1024-chunk sums
__global__ __launch_bounds__(256) void scan1_kernel(const int* __restrict__ deg,
                                                    int* __restrict__ blksum, int N) {
    __shared__ int s[256];
    int base = blockIdx.x * 1024 + threadIdx.x * 4;
    int sum = 0;
#pragma unroll
    for (int j = 0; j < 4; ++j) { int i = base + j; if (i < N) sum += deg[i]; }
    s[threadIdx.x] = sum;
    __syncthreads();
    for (int off = 128; off > 0; off >>= 1) {
        if (threadIdx.x < off) s[threadIdx.x] += s[threadIdx.x + off];
        __syncthreads();
    }
    if (threadIdx.x == 0) blksum[blockIdx.x] = s[0];
}

// scan phase 2: single-block exclusive scan of chunk sums (nblk <= 256)
__global__ __launch_bounds__(256) void scan2_kernel(const int* __restrict__ blksum,
                                                    int* __restrict__ blkoff, int nblk) {
    __shared__ int s[256];
    int t = threadIdx.x;
    int v = (t < nblk) ? blksum[t] : 0;
    s[t] = v;
    __syncthreads();
    for (int off = 1; off < 256; off <<= 1) {
        int add = (t >= off) ? s[t - off] : 0;
        __syncthreads();
        s[t] += add;
        __syncthreads();
    }
    if (t < nblk) blkoff[t] = s[t] - v;   // exclusive
}

// scan phase 3: per-element exclusive prefix -> rowptr; also init cursor(=deg)
__global__ __launch_bounds__(256) void scan3_kernel(int* __restrict__ deg,
                                                    const int* __restrict__ blkoff,
                                                    int* __restrict__ rowptr, int N) {
    __shared__ int s[256];
    int t = threadIdx.x;
    int base = blockIdx.x * 1024 + t * 4;
    int d[4];
    int loc = 0;
#pragma unroll
    for (int j = 0; j < 4; ++j) { int i = base + j; d[j] = (i < N) ? deg[i] : 0; loc += d[j]; }
    s[t] = loc;
    __syncthreads();
    for (int off = 1; off < 256; off <<= 1) {
        int add = (t >= off) ? s[t - off] : 0;
        __syncthreads();
        s[t] += add;
        __syncthreads();
    }
    int run = s[t] - loc + blkoff[blockIdx.x];   // exclusive prefix for this thread
#pragma unroll
    for (int j = 0; j < 4; ++j) {
        int i = base + j;
        if (i < N) {
            rowptr[i] = run;
            deg[i]    = run;        // reuse deg as the scatter cursor
            run += d[j];
            if (i == N - 1) rowptr[N] = run;
        }
    }
}

__global__ __launch_bounds__(256) void fill_kernel(const int* __restrict__ ei,
                                                   int* __restrict__ cursor,
                                                   int* __restrict__ esrc, int E) {
    int e = blockIdx.x * 256 + threadIdx.x;
    if (e >= E) return;
    int s = ei[e], d = ei[E + e];
    int pos = atomicAdd(&cursor[d], 1);
    esrc[pos] = s;
}

// ---------------------------------------------------------------------------
// K6: gather-reduce aggregate. One wave (64 lanes) per dst node; lane owns
// 2 features (float2). Zero atomics. Softmax shift-invariant, logits O(8),
// unshifted exp safe in fp32.
// ---------------------------------------------------------------------------
__global__ __launch_bounds__(256) void aggregate_kernel(const int* __restrict__ rowptr,
                                                        const int* __restrict__ esrc,
                                                        const float* __restrict__ hfeat,
                                                        const float* __restrict__ s_src,
                                                        const float* __restrict__ s_dst,
                                                        const float* __restrict__ bias,
                                                        float* __restrict__ out,
                                                        int N) {
    int wid  = threadIdx.x >> 6;           // wave in block (0..3)
    int lane = threadIdx.x & 63;
    int n = blockIdx.x * 4 + wid;
    if (n >= N) return;

    int f  = lane * 2;                     // this lane's 2 features
    int hh = lane >> 4;                    // head = f/32

    float sdst = s_dst[(size_t)n * 4 + hh];

    // self-loop message
    float e0 = s_src[(size_t)n * 4 + hh] + sdst;
    e0 = e0 > 0.f ? e0 : NEG_SLOPE * e0;
    float p0 = expf(e0);
    float2 hv = *(const float2*)(hfeat + (size_t)n * IN_F + f);
    float accx = p0 * hv.x, accy = p0 * hv.y, den = p0;

    int k0 = rowptr[n], k1 = rowptr[n + 1];
    for (int base = k0; base < k1; base += 64) {
        int cnt = k1 - base; if (cnt > 64) cnt = 64;
        int msrc = (lane < cnt) ? esrc[base + lane] : 0;
        for (int j = 0; j < cnt; ++j) {
            int src = __shfl(msrc, j);
            float ss = s_src[(size_t)src * 4 + hh];
            float ee = ss + sdst;
            ee = ee > 0.f ? ee : NEG_SLOPE * ee;
            float pp = expf(ee);
            float2 hs = *(const float2*)(hfeat + (size_t)src * IN_F + f);
            accx += pp * hs.x;
            accy += pp * hs.y;
            den  += pp;
        }
    }

    float inv = 1.f / (den + 1e-16f);
    float2 o;
    o.x = accx * inv + bias[f];
    o.y = accy * inv + bias[f + 1];
    *(float2*)(out + (size_t)n * IN_F + f) = o;
}

// ---------------------------------------------------------------------------
extern "C" void kernel_launch(void* const* d_in, const int* in_sizes, int n_in,
                              void* d_out, int out_size, void* d_ws, size_t ws_size,
                              hipStream_t stream) {
    const float* x       = (const float*)d_in[0];
    const int*   ei      = (const int*)d_in[1];   // harness stages integers as int32
    const float* W       = (const float*)d_in[2];
    const float* att_src = (const float*)d_in[3];
    const float* att_dst = (const float*)d_in[4];
    const float* bias    = (const float*)d_in[5];
    float*       out     = (float*)d_out;

    const int N = in_sizes[0] / IN_F;   // 100000
    const int E = in_sizes[1] / 2;      // 1600000

    // workspace layout
    char*  wsp    = (char*)d_ws;
    float* h      = (float*)wsp;                      wsp += (size_t)N * IN_F * 4;
    float* s_src  = (float*)wsp;                      wsp += (size_t)N * HEADS * 4;
    float* s_dst  = (float*)wsp;                      wsp += (size_t)N * HEADS * 4;
    int*   deg    = (int*)wsp;                        wsp += (size_t)N * 4;
    int*   rowptr = (int*)wsp;                        wsp += (size_t)(N + 1) * 4;
    int*   blksum = (int*)wsp;                        wsp += 256 * 4;
    int*   blkoff = (int*)wsp;                        wsp += 256 * 4;
    int*   esrc   = (int*)wsp;

    const int nblk_scan = (N + 1023) / 1024;          // 98 <= 256

    // histogram + projection + attention halves
    zero_deg_kernel<<<(N + 255) / 256, 256, 0, stream>>>(deg, N);
    count_kernel<<<(E + 255) / 256, 256, 0, stream>>>(ei, deg, E);
    gemm_kernel<<<(N + 31) / 32, 256, 0, stream>>>(x, W, h, N);
    {
        int n_groups = N * HEADS;
        int nthr = n_groups * 8;
        attn_halves_kernel<<<(nthr + 255) / 256, 256, 0, stream>>>(h, att_src, att_dst,
                                                                   s_src, s_dst, n_groups);
    }

    // exclusive scan deg -> rowptr (and cursor)
    scan1_kernel<<<nblk_scan, 256, 0, stream>>>(deg, blksum, N);
    scan2_kernel<<<1, 256, 0, stream>>>(blksum, blkoff, nblk_scan);
    scan3_kernel<<<nblk_scan, 256, 0, stream>>>(deg, blkoff, rowptr, N);

    // scatter sources into CSR
    fill_kernel<<<(E + 255) / 256, 256, 0, stream>>>(ei, deg, esrc, E);

    // gather-reduce per dst node
    aggregate_kernel<<<(N + 3) / 4, 256, 0, stream>>>(rowptr, esrc, h, s_src, s_dst,
                                                      bias, out, N);
}

// Round 5
// 479.921 us; speedup vs baseline: 7.2473x; 1.0437x over previous
//
#include <hip/hip_runtime.h>
#include <hip/hip_bf16.h>

#define IN_F 128
#define HEADS 4
#define OUT_F 32
#define NEG_SLOPE 0.2f

// ---------------------------------------------------------------------------
// K1: h = x @ W   (fp32 vector ALU — no fp32 MFMA on CDNA4)
// Register-blocked: block = 32 rows x 128 cols, thread = 4x4 tile.
// ---------------------------------------------------------------------------
__global__ __launch_bounds__(256) void gemm_kernel(const float* __restrict__ x,
                                                   const float* __restrict__ W,
                                                   float* __restrict__ h,
                                                   int n_nodes) {
    __shared__ float xs_t[128 * 36];   // [k][row], stride 36

    int tid = threadIdx.x;

    // ---- stage x tile (32 rows x 128 k), transposed ----
    {
        int row   = tid & 31;
        int kbase = (tid >> 5) << 4;           // 0,16,...,112
        int grow  = blockIdx.x * 32 + row;
        const float* xp = x + (size_t)grow * IN_F + kbase;
        bool ok = (grow < n_nodes);
#pragma unroll
        for (int j = 0; j < 4; ++j) {
            float4 xv = ok ? *(const float4*)(xp + j * 4)
                           : make_float4(0.f, 0.f, 0.f, 0.f);
            int k = kbase + j * 4;
            xs_t[(k + 0) * 36 + row] = xv.x;
            xs_t[(k + 1) * 36 + row] = xv.y;
            xs_t[(k + 2) * 36 + row] = xv.z;
            xs_t[(k + 3) * 36 + row] = xv.w;
        }
    }
    __syncthreads();

    // ---- compute 4 rows x 4 cols per thread ----
    int c4 = (tid & 31) << 2;
    int r4 = (tid >> 5) << 2;

    float4 acc0 = make_float4(0.f, 0.f, 0.f, 0.f);
    float4 acc1 = make_float4(0.f, 0.f, 0.f, 0.f);
    float4 acc2 = make_float4(0.f, 0.f, 0.f, 0.f);
    float4 acc3 = make_float4(0.f, 0.f, 0.f, 0.f);

#pragma unroll 8
    for (int k = 0; k < 128; ++k) {
        float4 xv = *(const float4*)(xs_t + k * 36 + r4);
        float4 wv = *(const float4*)(W + k * IN_F + c4);
        acc0.x += xv.x * wv.x; acc0.y += xv.x * wv.y; acc0.z += xv.x * wv.z; acc0.w += xv.x * wv.w;
        acc1.x += xv.y * wv.x; acc1.y += xv.y * wv.y; acc1.z += xv.y * wv.z; acc1.w += xv.y * wv.w;
        acc2.x += xv.z * wv.x; acc2.y += xv.z * wv.y; acc2.z += xv.z * wv.z; acc2.w += xv.z * wv.w;
        acc3.x += xv.w * wv.x; acc3.y += xv.w * wv.y; acc3.z += xv.w * wv.z; acc3.w += xv.w * wv.w;
    }

    int grow = blockIdx.x * 32 + r4;
    if (grow + 0 < n_nodes) *(float4*)(h + (size_t)(grow + 0) * IN_F + c4) = acc0;
    if (grow + 1 < n_nodes) *(float4*)(h + (size_t)(grow + 1) * IN_F + c4) = acc1;
    if (grow + 2 < n_nodes) *(float4*)(h + (size_t)(grow + 2) * IN_F + c4) = acc2;
    if (grow + 3 < n_nodes) *(float4*)(h + (size_t)(grow + 3) * IN_F + c4) = acc3;
}

// ---------------------------------------------------------------------------
// K2: per-node attention halves
// ---------------------------------------------------------------------------
__global__ __launch_bounds__(256) void attn_halves_kernel(const float* __restrict__ h,
                                                          const float* __restrict__ att_src,
                                                          const float* __restrict__ att_dst,
                                                          float* __restrict__ s_src,
                                                          float* __restrict__ s_dst,
                                                          int n_groups) {
    int gid   = blockIdx.x * 256 + threadIdx.x;
    int group = gid >> 3;      // (n, hh) pair
    int l8    = gid & 7;
    if (group >= n_groups) return;
    int hh = group & 3;

    float4 hv = *(const float4*)(h + (size_t)group * OUT_F + l8 * 4);
    float4 a1 = *(const float4*)(att_src + hh * OUT_F + l8 * 4);
    float4 a2 = *(const float4*)(att_dst + hh * OUT_F + l8 * 4);

    float ds_ = hv.x * a1.x + hv.y * a1.y + hv.z * a1.z + hv.w * a1.w;
    float dd_ = hv.x * a2.x + hv.y * a2.y + hv.z * a2.z + hv.w * a2.w;
    ds_ += __shfl_xor(ds_, 1); ds_ += __shfl_xor(ds_, 2); ds_ += __shfl_xor(ds_, 4);
    dd_ += __shfl_xor(dd_, 1); dd_ += __shfl_xor(dd_, 2); dd_ += __shfl_xor(dd_, 4);
    if (l8 == 0) { s_src[group] = ds_; s_dst[group] = dd_; }
}

// ---------------------------------------------------------------------------
// CSR build: histogram -> 3-phase exclusive scan -> scatter fill (+pexp)
// ---------------------------------------------------------------------------
__global__ __launch_bounds__(256) void zero_deg_kernel(int* __restrict__ deg, int n) {
    int i = blockIdx.x * 256 + threadIdx.x;
    if (i < n) deg[i] = 0;
}

__global__ __launch_bounds__(256) void count_kernel(const int* __restrict__ ei,
                                                    int* __restrict__ deg, int E) {
    int e = blockIdx.x * 256 + threadIdx.x;
    if (e < E) atomicAdd(&deg[ei[E + e]], 1);
}

__global__ __launch_bounds__(256) void scan1_kernel(const int* __restrict__ deg,
                                                    int* __restrict__ blksum, int N) {
    __shared__ int s[256];
    int base = blockIdx.x * 1024 + threadIdx.x * 4;
    int sum = 0;
#pragma unroll
    for (int j = 0; j < 4; ++j) { int i = base + j; if (i < N) sum += deg[i]; }
    s[threadIdx.x] = sum;
    __syncthreads();
    for (int off = 128; off > 0; off >>= 1) {
        if (threadIdx.x < off) s[threadIdx.x] += s[threadIdx.x + off];
        __syncthreads();
    }
    if (threadIdx.x == 0) blksum[blockIdx.x] = s[0];
}

__global__ __launch_bounds__(256) void scan2_kernel(const int* __restrict__ blksum,
                                                    int* __restrict__ blkoff, int nblk) {
    __shared__ int s[256];
    int t = threadIdx.x;
    int v = (t < nblk) ? blksum[t] : 0;
    s[t] = v;
    __syncthreads();
    for (int off = 1; off < 256; off <<= 1) {
        int add = (t >= off) ? s[t - off] : 0;
        __syncthreads();
        s[t] += add;
        __syncthreads();
    }
    if (t < nblk) blkoff[t] = s[t] - v;   // exclusive
}

__global__ __launch_bounds__(256) void scan3_kernel(int* __restrict__ deg,
                                                    const int* __restrict__ blkoff,
                                                    int* __restrict__ rowptr, int N) {
    __shared__ int s[256];
    int t = threadIdx.x;
    int base = blockIdx.x * 1024 + t * 4;
    int d[4];
    int loc = 0;
#pragma unroll
    for (int j = 0; j < 4; ++j) { int i = base + j; d[j] = (i < N) ? deg[i] : 0; loc += d[j]; }
    s[t] = loc;
    __syncthreads();
    for (int off = 1; off < 256; off <<= 1) {
        int add = (t >= off) ? s[t - off] : 0;
        __syncthreads();
        s[t] += add;
        __syncthreads();
    }
    int run = s[t] - loc + blkoff[blockIdx.x];
#pragma unroll
    for (int j = 0; j < 4; ++j) {
        int i = base + j;
        if (i < N) {
            rowptr[i] = run;
            deg[i]    = run;        // reuse deg as the scatter cursor
            run += d[j];
            if (i == N - 1) rowptr[N] = run;
        }
    }
}

// fill: scatter src ids AND per-edge softmax numerators exp(leaky(e)) per head.
// s_src/s_dst are 1.6MB each -> L2-resident gathers. One float4 store per edge.
__global__ __launch_bounds__(256) void fill_kernel(const int* __restrict__ ei,
                                                   int* __restrict__ cursor,
                                                   const float* __restrict__ s_src,
                                                   const float* __restrict__ s_dst,
                                                   int* __restrict__ esrc,
                                                   float4* __restrict__ pexp, int E) {
    int e = blockIdx.x * 256 + threadIdx.x;
    if (e >= E) return;
    int s = ei[e], d = ei[E + e];
    int pos = atomicAdd(&cursor[d], 1);
    esrc[pos] = s;

    float4 as = *(const float4*)(s_src + ((size_t)s << 2));
    float4 ad = *(const float4*)(s_dst + ((size_t)d << 2));
    float v0 = as.x + ad.x, v1 = as.y + ad.y, v2 = as.z + ad.z, v3 = as.w + ad.w;
    v0 = v0 > 0.f ? v0 : NEG_SLOPE * v0;
    v1 = v1 > 0.f ? v1 : NEG_SLOPE * v1;
    v2 = v2 > 0.f ? v2 : NEG_SLOPE * v2;
    v3 = v3 > 0.f ? v3 : NEG_SLOPE * v3;
    float4 p; p.x = expf(v0); p.y = expf(v1); p.z = expf(v2); p.w = expf(v3);
    pexp[pos] = p;
}

// ---------------------------------------------------------------------------
// K6: gather-reduce aggregate. One wave per dst node; lane owns 2 features.
// Inner loop: shfl src + broadcast pexp dword (L1-sequential) + float2 h row
// + 2 FMA. All attention math precomputed in fill. 32-bit addressing.
// ---------------------------------------------------------------------------
__global__ __launch_bounds__(256) void aggregate_kernel(const int* __restrict__ rowptr,
                                                        const int* __restrict__ esrc,
                                                        const float4* __restrict__ pexp,
                                                        const float* __restrict__ hfeat,
                                                        const float* __restrict__ s_src,
                                                        const float* __restrict__ s_dst,
                                                        const float* __restrict__ bias,
                                                        float* __restrict__ out,
                                                        int N) {
    int wid  = threadIdx.x >> 6;
    int lane = threadIdx.x & 63;
    int n = blockIdx.x * 4 + wid;
    if (n >= N) return;

    unsigned f  = (unsigned)lane * 2u;     // this lane's 2 features
    int      hh = lane >> 4;               // head

    const float* pexp_f = (const float*)pexp;

    // self-loop message
    float e0 = s_src[((unsigned)n << 2) + hh] + s_dst[((unsigned)n << 2) + hh];
    e0 = e0 > 0.f ? e0 : NEG_SLOPE * e0;
    float p0 = expf(e0);
    float2 hv = *(const float2*)(hfeat + (((unsigned)n << 7) | f));
    float accx = p0 * hv.x, accy = p0 * hv.y, den = p0;

    int k0 = rowptr[n], k1 = rowptr[n + 1];
    for (int base = k0; base < k1; base += 64) {
        int cnt = k1 - base; if (cnt > 64) cnt = 64;
        int msrc = (lane < cnt) ? esrc[base + lane] : 0;
#pragma unroll 4
        for (int j = 0; j < cnt; ++j) {
            int src = __shfl(msrc, j);
            float pp = pexp_f[(((unsigned)(base + j)) << 2) | (unsigned)hh];
            float2 hs = *(const float2*)(hfeat + (((unsigned)src << 7) | f));
            accx += pp * hs.x;
            accy += pp * hs.y;
            den  += pp;
        }
    }

    float inv = 1.f / (den + 1e-16f);
    float2 o;
    o.x = accx * inv + bias[f];
    o.y = accy * inv + bias[f + 1];
    *(float2*)(out + (((unsigned)n << 7) | f)) = o;
}

// ---------------------------------------------------------------------------
extern "C" void kernel_launch(void* const* d_in, const int* in_sizes, int n_in,
                              void* d_out, int out_size, void* d_ws, size_t ws_size,
                              hipStream_t stream) {
    const float* x       = (const float*)d_in[0];
    const int*   ei      = (const int*)d_in[1];   // harness stages integers as int32
    const float* W       = (const float*)d_in[2];
    const float* att_src = (const float*)d_in[3];
    const float* att_dst = (const float*)d_in[4];
    const float* bias    = (const float*)d_in[5];
    float*       out     = (float*)d_out;

    const int N = in_sizes[0] / IN_F;   // 100000
    const int E = in_sizes[1] / 2;      // 1600000

    // workspace layout (~87 MB)
    char*   wsp    = (char*)d_ws;
    float*  h      = (float*)wsp;                     wsp += (size_t)N * IN_F * 4;
    float*  s_src  = (float*)wsp;                     wsp += (size_t)N * HEADS * 4;
    float*  s_dst  = (float*)wsp;                     wsp += (size_t)N * HEADS * 4;
    int*    deg    = (int*)wsp;                       wsp += (size_t)N * 4;
    int*    rowptr = (int*)wsp;                       wsp += (size_t)(N + 1) * 4;
    int*    blksum = (int*)wsp;                       wsp += 256 * 4;
    int*    blkoff = (int*)wsp;                       wsp += 256 * 4;
    int*    esrc   = (int*)wsp;                       wsp += (size_t)E * 4;
    float4* pexp   = (float4*)wsp;                    // E * 16 bytes

    const int nblk_scan = (N + 1023) / 1024;          // 98 <= 256

    zero_deg_kernel<<<(N + 255) / 256, 256, 0, stream>>>(deg, N);
    count_kernel<<<(E + 255) / 256, 256, 0, stream>>>(ei, deg, E);
    gemm_kernel<<<(N + 31) / 32, 256, 0, stream>>>(x, W, h, N);
    {
        int n_groups = N * HEADS;
        int nthr = n_groups * 8;
        attn_halves_kernel<<<(nthr + 255) / 256, 256, 0, stream>>>(h, att_src, att_dst,
                                                                   s_src, s_dst, n_groups);
    }

    scan1_kernel<<<nblk_scan, 256, 0, stream>>>(deg, blksum, N);
    scan2_kernel<<<1, 256, 0, stream>>>(blksum, blkoff, nblk_scan);
    scan3_kernel<<<nblk_scan, 256, 0, stream>>>(deg, blkoff, rowptr, N);

    fill_kernel<<<(E + 255) / 256, 256, 0, stream>>>(ei, deg, s_src, s_dst, esrc, pexp, E);

    aggregate_kernel<<<(N + 3) / 4, 256, 0, stream>>>(rowptr, esrc, pexp, h,
                                                      s_src, s_dst, bias, out, N);
}

// Round 8
// 442.677 us; speedup vs baseline: 7.8570x; 1.0841x over previous
//
#include <hip/hip_runtime.h>
#include <hip/hip_fp16.h>

#define IN_F 128
#define HEADS 4
#define OUT_F 32
#define NEG_SLOPE 0.2f

// ---------------------------------------------------------------------------
// K1: h = x @ W fused with per-node attention halves.
// Register-blocked: block = 32 rows x 128 cols, thread = 4x4 tile.
// Epilogue: (a) h stored as fp16 only (halves gather bytes downstream),
// (b) s_src/s_dst = dot(h_row, att_{src,dst}[head]) computed from the fp32
// accumulators via segmented 8-lane shfl_xor reduce (full precision logits).
// ---------------------------------------------------------------------------
__global__ __launch_bounds__(256) void gemm_fused_kernel(const float* __restrict__ x,
                                                         const float* __restrict__ W,
                                                         const float* __restrict__ att_src,
                                                         const float* __restrict__ att_dst,
                                                         __half* __restrict__ h16,
                                                         float* __restrict__ s_src,
                                                         float* __restrict__ s_dst,
                                                         int n_nodes) {
    __shared__ float xs_t[128 * 36];   // [k][row], stride 36

    int tid = threadIdx.x;

    // ---- stage x tile (32 rows x 128 k), transposed ----
    {
        int row   = tid & 31;
        int kbase = (tid >> 5) << 4;           // 0,16,...,112
        int grow  = blockIdx.x * 32 + row;
        const float* xp = x + (size_t)grow * IN_F + kbase;
        bool ok = (grow < n_nodes);
#pragma unroll
        for (int j = 0; j < 4; ++j) {
            float4 xv = ok ? *(const float4*)(xp + j * 4)
                           : make_float4(0.f, 0.f, 0.f, 0.f);
            int k = kbase + j * 4;
            xs_t[(k + 0) * 36 + row] = xv.x;
            xs_t[(k + 1) * 36 + row] = xv.y;
            xs_t[(k + 2) * 36 + row] = xv.z;
            xs_t[(k + 3) * 36 + row] = xv.w;
        }
    }
    __syncthreads();

    // ---- compute 4 rows x 4 cols per thread ----
    int c4 = (tid & 31) << 2;
    int r4 = (tid >> 5) << 2;

    float4 acc0 = make_float4(0.f, 0.f, 0.f, 0.f);
    float4 acc1 = make_float4(0.f, 0.f, 0.f, 0.f);
    float4 acc2 = make_float4(0.f, 0.f, 0.f, 0.f);
    float4 acc3 = make_float4(0.f, 0.f, 0.f, 0.f);

#pragma unroll 8
    for (int k = 0; k < 128; ++k) {
        float4 xv = *(const float4*)(xs_t + k * 36 + r4);
        float4 wv = *(const float4*)(W + k * IN_F + c4);
        acc0.x += xv.x * wv.x; acc0.y += xv.x * wv.y; acc0.z += xv.x * wv.z; acc0.w += xv.x * wv.w;
        acc1.x += xv.y * wv.x; acc1.y += xv.y * wv.y; acc1.z += xv.y * wv.z; acc1.w += xv.y * wv.w;
        acc2.x += xv.z * wv.x; acc2.y += xv.z * wv.y; acc2.z += xv.z * wv.z; acc2.w += xv.z * wv.w;
        acc3.x += xv.w * wv.x; acc3.y += xv.w * wv.y; acc3.z += xv.w * wv.z; acc3.w += xv.w * wv.w;
    }

    int grow = blockIdx.x * 32 + r4;

    // ---- store h as fp16 ----
#pragma unroll
    for (int r = 0; r < 4; ++r) {
        float4 a = (r == 0) ? acc0 : (r == 1) ? acc1 : (r == 2) ? acc2 : acc3;
        if (grow + r < n_nodes) {
            __half2 pa = __floats2half2_rn(a.x, a.y);
            __half2 pb = __floats2half2_rn(a.z, a.w);
            __half* hp = h16 + (((unsigned)(grow + r)) << 7) + c4;
            *(__half2*)(hp + 0) = pa;
            *(__half2*)(hp + 2) = pb;
        }
    }

    // ---- fused attention halves (full fp32 precision) ----
    int hh = c4 >> 5;          // head of this thread's 4 cols
    int cw = c4 & 31;          // within-head col
    float4 asv = *(const float4*)(att_src + (hh << 5) + cw);
    float4 adv = *(const float4*)(att_dst + (hh << 5) + cw);

    float ps0 = acc0.x*asv.x + acc0.y*asv.y + acc0.z*asv.z + acc0.w*asv.w;
    float ps1 = acc1.x*asv.x + acc1.y*asv.y + acc1.z*asv.z + acc1.w*asv.w;
    float ps2 = acc2.x*asv.x + acc2.y*asv.y + acc2.z*asv.z + acc2.w*asv.w;
    float ps3 = acc3.x*asv.x + acc3.y*asv.y + acc3.z*asv.z + acc3.w*asv.w;
    float pd0 = acc0.x*adv.x + acc0.y*adv.y + acc0.z*adv.z + acc0.w*adv.w;
    float pd1 = acc1.x*adv.x + acc1.y*adv.y + acc1.z*adv.z + acc1.w*adv.w;
    float pd2 = acc2.x*adv.x + acc2.y*adv.y + acc2.z*adv.z + acc2.w*adv.w;
    float pd3 = acc3.x*adv.x + acc3.y*adv.y + acc3.z*adv.z + acc3.w*adv.w;

    // segmented reduce over the 8 lanes sharing (row-quad, head)
#pragma unroll
    for (int m = 1; m <= 4; m <<= 1) {
        ps0 += __shfl_xor(ps0, m); pd0 += __shfl_xor(pd0, m);
        ps1 += __shfl_xor(ps1, m); pd1 += __shfl_xor(pd1, m);
        ps2 += __shfl_xor(ps2, m); pd2 += __shfl_xor(pd2, m);
        ps3 += __shfl_xor(ps3, m); pd3 += __shfl_xor(pd3, m);
    }

    if ((tid & 7) == 0) {
#pragma unroll
        for (int r = 0; r < 4; ++r) {
            float ps = (r == 0) ? ps0 : (r == 1) ? ps1 : (r == 2) ? ps2 : ps3;
            float pd = (r == 0) ? pd0 : (r == 1) ? pd1 : (r == 2) ? pd2 : pd3;
            int n = grow + r;
            if (n < n_nodes) {
                s_src[((unsigned)n << 2) + hh] = ps;
                s_dst[((unsigned)n << 2) + hh] = pd;
            }
        }
    }
}

// ---------------------------------------------------------------------------
// CSR build: histogram -> 3-phase exclusive scan -> scatter fill (+pexp)
// ---------------------------------------------------------------------------
__global__ __launch_bounds__(256) void count_kernel(const int* __restrict__ ei,
                                                    int* __restrict__ deg, int E) {
    int e = blockIdx.x * 256 + threadIdx.x;
    if (e < E) atomicAdd(&deg[ei[E + e]], 1);
}

__global__ __launch_bounds__(256) void scan1_kernel(const int* __restrict__ deg,
                                                    int* __restrict__ blksum, int N) {
    __shared__ int s[256];
    int base = blockIdx.x * 1024 + threadIdx.x * 4;
    int sum = 0;
#pragma unroll
    for (int j = 0; j < 4; ++j) { int i = base + j; if (i < N) sum += deg[i]; }
    s[threadIdx.x] = sum;
    __syncthreads();
    for (int off = 128; off > 0; off >>= 1) {
        if (threadIdx.x < off) s[threadIdx.x] += s[threadIdx.x + off];
        __syncthreads();
    }
    if (threadIdx.x == 0) blksum[blockIdx.x] = s[0];
}

__global__ __launch_bounds__(256) void scan2_kernel(const int* __restrict__ blksum,
                                                    int* __restrict__ blkoff, int nblk) {
    __shared__ int s[256];
    int t = threadIdx.x;
    int v = (t < nblk) ? blksum[t] : 0;
    s[t] = v;
    __syncthreads();
    for (int off = 1; off < 256; off <<= 1) {
        int add = (t >= off) ? s[t - off] : 0;
        __syncthreads();
        s[t] += add;
        __syncthreads();
    }
    if (t < nblk) blkoff[t] = s[t] - v;   // exclusive
}

__global__ __launch_bounds__(256) void scan3_kernel(int* __restrict__ deg,
                                                    const int* __restrict__ blkoff,
                                                    int* __restrict__ rowptr, int N) {
    __shared__ int s[256];
    int t = threadIdx.x;
    int base = blockIdx.x * 1024 + t * 4;
    int d[4];
    int loc = 0;
#pragma unroll
    for (int j = 0; j < 4; ++j) { int i = base + j; d[j] = (i < N) ? deg[i] : 0; loc += d[j]; }
    s[t] = loc;
    __syncthreads();
    for (int off = 1; off < 256; off <<= 1) {
        int add = (t >= off) ? s[t - off] : 0;
        __syncthreads();
        s[t] += add;
        __syncthreads();
    }
    int run = s[t] - loc + blkoff[blockIdx.x];
#pragma unroll
    for (int j = 0; j < 4; ++j) {
        int i = base + j;
        if (i < N) {
            rowptr[i] = run;
            deg[i]    = run;        // reuse deg as the scatter cursor
            run += d[j];
            if (i == N - 1) rowptr[N] = run;
        }
    }
}

// fill: scatter src ids AND per-edge softmax numerators exp(leaky(e)) per head.
__global__ __launch_bounds__(256) void fill_kernel(const int* __restrict__ ei,
                                                   int* __restrict__ cursor,
                                                   const float* __restrict__ s_src,
                                                   const float* __restrict__ s_dst,
                                                   int* __restrict__ esrc,
                                                   float4* __restrict__ pexp, int E) {
    int e = blockIdx.x * 256 + threadIdx.x;
    if (e >= E) return;
    int s = ei[e], d = ei[E + e];
    int pos = atomicAdd(&cursor[d], 1);
    esrc[pos] = s;

    float4 as = *(const float4*)(s_src + ((size_t)s << 2));
    float4 ad = *(const float4*)(s_dst + ((size_t)d << 2));
    float v0 = as.x + ad.x, v1 = as.y + ad.y, v2 = as.z + ad.z, v3 = as.w + ad.w;
    v0 = v0 > 0.f ? v0 : NEG_SLOPE * v0;
    v1 = v1 > 0.f ? v1 : NEG_SLOPE * v1;
    v2 = v2 > 0.f ? v2 : NEG_SLOPE * v2;
    v3 = v3 > 0.f ? v3 : NEG_SLOPE * v3;
    float4 p; p.x = expf(v0); p.y = expf(v1); p.z = expf(v2); p.w = expf(v3);
    pexp[pos] = p;
}

// ---------------------------------------------------------------------------
// K6: gather-reduce aggregate. One wave per dst node; lane owns 2 features.
// fp16 h gather (4 B/lane/edge), readlane -> SGPR row base, unroll 8.
// ---------------------------------------------------------------------------
__global__ __launch_bounds__(256) void aggregate_kernel(const int* __restrict__ rowptr,
                                                        const int* __restrict__ esrc,
                                                        const float4* __restrict__ pexp,
                                                        const __half* __restrict__ h16,
                                                        const float* __restrict__ s_src,
                                                        const float* __restrict__ s_dst,
                                                        const float* __restrict__ bias,
                                                        float* __restrict__ out,
                                                        int N) {
    int wid  = threadIdx.x >> 6;
    int lane = threadIdx.x & 63;
    int n = blockIdx.x * 4 + wid;
    if (n >= N) return;

    unsigned f  = (unsigned)lane * 2u;     // this lane's 2 features
    int      hh = lane >> 4;               // head

    const float* pexp_f = (const float*)pexp;

    // self-loop message
    float e0 = s_src[((unsigned)n << 2) + hh] + s_dst[((unsigned)n << 2) + hh];
    e0 = e0 > 0.f ? e0 : NEG_SLOPE * e0;
    float p0 = expf(e0);
    float2 hv = __half22float2(*(const __half2*)(h16 + (((unsigned)n << 7) | f)));
    float accx = p0 * hv.x, accy = p0 * hv.y, den = p0;

    int k0 = rowptr[n], k1 = rowptr[n + 1];
    for (int base = k0; base < k1; base += 64) {
        int cnt = k1 - base; if (cnt > 64) cnt = 64;
        int msrc = (lane < cnt) ? esrc[base + lane] : 0;
#pragma unroll 8
        for (int j = 0; j < cnt; ++j) {
            int src = __builtin_amdgcn_readlane(msrc, j);   // j wave-uniform -> SGPR
            float pp = pexp_f[(((unsigned)(base + j)) << 2) | (unsigned)hh];
            float2 hs = __half22float2(*(const __half2*)(h16 + (((unsigned)src << 7) | f)));
            accx += pp * hs.x;
            accy += pp * hs.y;
            den  += pp;
        }
    }

    float inv = 1.f / (den + 1e-16f);
    float2 o;
    o.x = accx * inv + bias[f];
    o.y = accy * inv + bias[f + 1];
    *(float2*)(out + (((unsigned)n << 7) | f)) = o;
}

// ---------------------------------------------------------------------------
extern "C" void kernel_launch(void* const* d_in, const int* in_sizes, int n_in,
                              void* d_out, int out_size, void* d_ws, size_t ws_size,
                              hipStream_t stream) {
    const float* x       = (const float*)d_in[0];
    const int*   ei      = (const int*)d_in[1];   // harness stages integers as int32
    const float* W       = (const float*)d_in[2];
    const float* att_src = (const float*)d_in[3];
    const float* att_dst = (const float*)d_in[4];
    const float* bias    = (const float*)d_in[5];
    float*       out     = (float*)d_out;

    const int N = in_sizes[0] / IN_F;   // 100000
    const int E = in_sizes[1] / 2;      // 1600000

    // workspace layout (~61 MB): pexp first for 16-B alignment
    char*   wsp    = (char*)d_ws;
    float4* pexp   = (float4*)wsp;                    wsp += (size_t)E * 16;
    __half* h16    = (__half*)wsp;                    wsp += (size_t)N * IN_F * 2;
    float*  s_src  = (float*)wsp;                     wsp += (size_t)N * HEADS * 4;
    float*  s_dst  = (float*)wsp;                     wsp += (size_t)N * HEADS * 4;
    int*    esrc   = (int*)wsp;                       wsp += (size_t)E * 4;
    int*    deg    = (int*)wsp;                       wsp += (size_t)N * 4;
    int*    rowptr = (int*)wsp;                       wsp += (size_t)(N + 1) * 4;
    int*    blksum = (int*)wsp;                       wsp += 256 * 4;
    int*    blkoff = (int*)wsp;

    const int nblk_scan = (N + 1023) / 1024;          // 98 <= 256

    hipMemsetAsync(deg, 0, (size_t)N * 4, stream);
    count_kernel<<<(E + 255) / 256, 256, 0, stream>>>(ei, deg, E);
    gemm_fused_kernel<<<(N + 31) / 32, 256, 0, stream>>>(x, W, att_src, att_dst,
                                                         h16, s_src, s_dst, N);

    scan1_kernel<<<nblk_scan, 256, 0, stream>>>(deg, blksum, N);
    scan2_kernel<<<1, 256, 0, stream>>>(blksum, blkoff, nblk_scan);
    scan3_kernel<<<1 + (N + 1023) / 1024 - 1, 256, 0, stream>>>(deg, blkoff, rowptr, N);

    fill_kernel<<<(E + 255) / 256, 256, 0, stream>>>(ei, deg, s_src, s_dst, esrc, pexp, E);

    aggregate_kernel<<<(N + 3) / 4, 256, 0, stream>>>(rowptr, esrc, pexp, h16,
                                                      s_src, s_dst, bias, out, N);
}